// Round 13
// baseline (923.518 us; speedup 1.0000x reference)
//
#include <hip/hip_runtime.h>
#include <hip/hip_bf16.h>

#define NN 16384      // nodes
#define NE 262144     // edges
#define HIDD 1024
#define DD 768
#define RR 6
#define BB 4
#define LL 2
#define BN_EPS 1e-5f
#define LN_EPS 1e-5f

typedef __attribute__((ext_vector_type(8))) short bf16x8;
typedef __attribute__((ext_vector_type(4))) float f32x4;

__device__ __forceinline__ float b2f(unsigned short u) {
  union { unsigned int i; float f; } c;
  c.i = ((unsigned int)u) << 16;
  return c.f;
}
__device__ __forceinline__ unsigned short f2b(float f) {  // RNE
  union { float f; unsigned int u; } c;
  c.f = f;
  unsigned int x = c.u;
  x += 0x7FFFu + ((x >> 16) & 1u);
  return (unsigned short)(x >> 16);
}

__device__ __forceinline__ void gll16(const unsigned short* g, unsigned short* l) {
  __builtin_amdgcn_global_load_lds(
      (const __attribute__((address_space(1))) unsigned int*)g,
      (__attribute__((address_space(3))) unsigned int*)l, 16, 0, 0);
}

// dtype detector: flag=1 -> inputs f32, flag=0 -> inputs bf16.
__global__ void k_detect(const unsigned short* __restrict__ h, int* __restrict__ flag) {
  __shared__ int sh[256];
  int cnt = 0;
  for (int k = 0; k < 256; ++k) {
    ushort4 t = *(const ushort4*)&h[(size_t)(k * 256 + threadIdx.x) * 4];
    if ((t.x & 0x7F80) == 0x7F80) cnt++;
    if ((t.y & 0x7F80) == 0x7F80) cnt++;
    if ((t.z & 0x7F80) == 0x7F80) cnt++;
    if ((t.w & 0x7F80) == 0x7F80) cnt++;
  }
  sh[threadIdx.x] = cnt;
  __syncthreads();
  if (threadIdx.x == 0) {
    int t = 0;
    for (int i = 0; i < 256; ++i) t += sh[i];
    flag[0] = (t > 16) ? 1 : 0;
  }
}

// MODE: 0 = raw input (flag-dependent), 1 = f32, 2 = bf16
template <int MODE>
__device__ __forceinline__ float load1t(const void* p, size_t i, int isf32) {
  if (MODE == 1 || (MODE == 0 && isf32)) return ((const float*)p)[i];
  return b2f(((const unsigned short*)p)[i]);
}

// batched param conversion: 8 segments -> fpar
__global__ void k_cvt8(const void* s0, const void* s1, const void* s2, const void* s3,
                       const void* s4, const void* s5, const void* s6, const void* s7,
                       float* __restrict__ fpar, const int* __restrict__ flagp) {
  const int isf32 = flagp[0];
  const int seg = blockIdx.y;
  const int lens[8] = {768, 48, 1536, 1536, 1536, 1024, 1024, 1024};
  const int offs_[8] = {0, 768, 816, 2352, 3888, 5424, 6448, 7472};
  const void* srcs[8] = {s0, s1, s2, s3, s4, s5, s6, s7};
  int i = blockIdx.x * 256 + threadIdx.x;
  if (i < lens[seg]) fpar[offs_[seg] + i] = load1t<0>(srcs[seg], i, isf32);
}

// raw input -> bf16 copy
__global__ void k_cvtb(const void* __restrict__ in, unsigned short* __restrict__ out,
                       int n, const int* __restrict__ flagp) {
  const int isf32 = flagp[0];
  int i = blockIdx.x * 256 + threadIdx.x;
  if (i < n) out[i] = f2b(load1t<0>(in, (size_t)i, isf32));
}

// diagnostic fill (f32 out)
__global__ void k_fill(float* __restrict__ out, long n, float val) {
  long i = (long)blockIdx.x * 256 + threadIdx.x;
  if (i < n) out[i] = val;
}

// LDS-tiled transpose: src [I][J] (flag dtype) -> dst[j*dstStride + dstOff + i] bf16.
__global__ __launch_bounds__(256) void k_transpose(const void* __restrict__ src,
                                                   long ioff,
                                                   unsigned short* __restrict__ dst,
                                                   int I, int J, int dstStride,
                                                   int dstOff,
                                                   const int* __restrict__ flagp) {
  const int isf32 = flagp[0];
  __shared__ unsigned short t[64][65];
  const int j0 = blockIdx.x * 64, i0 = blockIdx.y * 64;
  const int tx = threadIdx.x & 63, ty = threadIdx.x >> 6;
  for (int rr = ty; rr < 64; rr += 4)
    t[rr][tx] = f2b(load1t<0>(src, (size_t)ioff + (size_t)(i0 + rr) * J + j0 + tx, isf32));
  __syncthreads();
  for (int rr = ty; rr < 64; rr += 4)
    dst[(size_t)(j0 + rr) * dstStride + dstOff + i0 + tx] = t[tx][rr];
}

// batched: BTcat[n][z*768 + k] = W_z[k][n], z=0 root, z=1..4 basis[z-1]
__global__ __launch_bounds__(256) void k_tbatch(const void* __restrict__ root, long roff,
                                                const void* __restrict__ basis, long boff,
                                                unsigned short* __restrict__ BT,
                                                const int* __restrict__ flagp) {
  const int isf32 = flagp[0];
  const int z = blockIdx.z;
  const void* src = (z == 0) ? root : basis;
  const long off = (z == 0) ? roff : boff + (long)(z - 1) * DD * DD;
  __shared__ unsigned short t[64][65];
  const int j0 = blockIdx.x * 64, i0 = blockIdx.y * 64;
  const int tx = threadIdx.x & 63, ty = threadIdx.x >> 6;
  for (int rr = ty; rr < 64; rr += 4)
    t[rr][tx] = f2b(load1t<0>(src, (size_t)off + (size_t)(i0 + rr) * DD + j0 + tx, isf32));
  __syncthreads();
  for (int rr = ty; rr < 64; rr += 4)
    BT[(size_t)(j0 + rr) * (5 * DD) + z * DD + i0 + tx] = t[tx][rr];
}

// ---------------------------------------------------------------------------
// MFMA bf16 GEMM: C[M,N] = A[M,K] @ Bt[N,K]^T (+bias)(relu)
// 128x128 tile, 4 waves, BK=32, 16x16x32 MFMA.
// 2-PHASE PIPELINE: double-buffered LDS; next tile's global_load_lds issued
// BEFORE current tile's ds_read+MFMA; ONE barrier per K-step (implicit
// vmcnt(0) drain lands after compute -> HBM latency hidden).
// Coalesced quad staging + XOR slot permutation (2-way banks). XCD swizzle.
// ---------------------------------------------------------------------------
template <int BIAS, int RELU, int OUTB>
__global__ __launch_bounds__(256) void k_mgemm(const unsigned short* __restrict__ A,
                                               const unsigned short* __restrict__ Bt,
                                               const float* __restrict__ bias,
                                               void* __restrict__ C,
                                               int M, int Nn, int K) {
  __shared__ __align__(16) unsigned short Alds[2][128 * 32];
  __shared__ __align__(16) unsigned short Blds[2][128 * 32];
  const int tid = threadIdx.x;
  const int lane = tid & 63, w = tid >> 6;
  const int wm = w >> 1, wn = w & 1;
  const int fr = lane & 15, kg = lane >> 4;
  const int nwg = gridDim.x;
  int id = blockIdx.x;
  if ((nwg & 7) == 0) id = (id & 7) * (nwg >> 3) + (id >> 3);
  const int gx = Nn >> 7;
  const int m0 = (id / gx) * 128, n0 = (id % gx) * 128;

  const int srow = w * 16 + (lane >> 2);
  const int sslot = (lane & 3) ^ ((lane >> 3) & 3);
  const unsigned short* ga = A + (size_t)(m0 + srow) * K + sslot * 8;
  const unsigned short* ga2 = ga + (size_t)64 * K;
  const unsigned short* gb = Bt + (size_t)(n0 + srow) * K + sslot * 8;
  const unsigned short* gb2 = gb + (size_t)64 * K;
  const int wo = w * 512;
  const int roff = fr * 32 + ((kg ^ ((fr >> 1) & 3)) * 8);

  f32x4 acc[4][4] = {};

  // prologue: stage tile 0 into buf 0
  gll16(ga, &Alds[0][wo]);
  gll16(ga2, &Alds[0][wo + 2048]);
  gll16(gb, &Blds[0][wo]);
  gll16(gb2, &Blds[0][wo + 2048]);
  __syncthreads();

  for (int k0 = 0; k0 < K; k0 += 32) {
    const int cur = (k0 >> 5) & 1;
    const int nxt = cur ^ 1;
    if (k0 + 32 < K) {   // stage next tile (overlaps with compute below)
      gll16(ga + k0 + 32, &Alds[nxt][wo]);
      gll16(ga2 + k0 + 32, &Alds[nxt][wo + 2048]);
      gll16(gb + k0 + 32, &Blds[nxt][wo]);
      gll16(gb2 + k0 + 32, &Blds[nxt][wo + 2048]);
    }
    bf16x8 af[4], bfr[4];
#pragma unroll
    for (int i = 0; i < 4; ++i) {
      af[i] = *(const bf16x8*)(&Alds[cur][(wm * 4 + i) * 512 + roff]);
      bfr[i] = *(const bf16x8*)(&Blds[cur][(wn * 4 + i) * 512 + roff]);
    }
#pragma unroll
    for (int i = 0; i < 4; ++i)
#pragma unroll
      for (int j = 0; j < 4; ++j)
        acc[i][j] = __builtin_amdgcn_mfma_f32_16x16x32_bf16(af[i], bfr[j],
                                                            acc[i][j], 0, 0, 0);
    __syncthreads();   // single barrier: drains stage, protects buf reuse
  }

  const int orow = (lane >> 4) * 4;
#pragma unroll
  for (int i = 0; i < 4; ++i) {
#pragma unroll
    for (int j = 0; j < 4; ++j) {
      const int n = n0 + wn * 64 + j * 16 + fr;
      const float bv = BIAS ? bias[n] : 0.f;
#pragma unroll
      for (int rg = 0; rg < 4; ++rg) {
        const int m = m0 + wm * 64 + i * 16 + orow + rg;
        const size_t off = (size_t)m * Nn + n;
        float v = acc[i][j][rg] + bv;
        if (RELU) v = fmaxf(v, 0.f);
        if (OUTB) ((unsigned short*)C)[off] = f2b(v);
        else      ((float*)C)[off] = v;
      }
    }
  }
}

// ---------------------------------------------------------------------------
// Fused layer GEMM: xc[N][768] = [x0 | Y01 | Y23][N][3840] @ BTcat[768][3840]^T
// Same 2-phase pipeline. grid = 768.
// ---------------------------------------------------------------------------
__global__ __launch_bounds__(256) void k_mgemm3(const unsigned short* __restrict__ x0,
                                                const unsigned short* __restrict__ Y01,
                                                const unsigned short* __restrict__ Y23,
                                                const unsigned short* __restrict__ BT,
                                                float* __restrict__ C) {
  __shared__ __align__(16) unsigned short Alds[2][128 * 32];
  __shared__ __align__(16) unsigned short Blds[2][128 * 32];
  const int tid = threadIdx.x;
  const int lane = tid & 63, w = tid >> 6;
  const int wm = w >> 1, wn = w & 1;
  const int fr = lane & 15, kg = lane >> 4;
  const int nwg = gridDim.x;        // 768
  int id = blockIdx.x;
  id = (id & 7) * (nwg >> 3) + (id >> 3);
  const int m0 = (id / 6) * 128, n0 = (id % 6) * 128;

  const int srow = w * 16 + (lane >> 2);
  const int sslot = (lane & 3) ^ ((lane >> 3) & 3);
  const unsigned short* gxp = x0 + (size_t)(m0 + srow) * DD + sslot * 8;
  const unsigned short* gxp2 = gxp + (size_t)64 * DD;
  const unsigned short* gy = Y01 + (size_t)(m0 + srow) * 1536 + sslot * 8;
  const unsigned short* gy2 = gy + (size_t)64 * 1536;
  const unsigned short* gz = Y23 + (size_t)(m0 + srow) * 1536 + sslot * 8;
  const unsigned short* gz2 = gz + (size_t)64 * 1536;
  const unsigned short* gb = BT + (size_t)(n0 + srow) * 3840 + sslot * 8;
  const unsigned short* gb2 = gb + (size_t)64 * 3840;
  const int wo = w * 512;
  const int roff = fr * 32 + ((kg ^ ((fr >> 1) & 3)) * 8);

  f32x4 acc[4][4] = {};

  // stage K-tile k0 into buffer b
  auto stage = [&](int k0, int b) {
    const unsigned short *pa, *pa2;
    if (k0 < 768)       { pa = gxp + k0;       pa2 = gxp2 + k0; }
    else if (k0 < 2304) { pa = gy + k0 - 768;  pa2 = gy2 + k0 - 768; }
    else                { pa = gz + k0 - 2304; pa2 = gz2 + k0 - 2304; }
    gll16(pa, &Alds[b][wo]);
    gll16(pa2, &Alds[b][wo + 2048]);
    gll16(gb + k0, &Blds[b][wo]);
    gll16(gb2 + k0, &Blds[b][wo + 2048]);
  };

  stage(0, 0);
  __syncthreads();

  for (int k0 = 0; k0 < 3840; k0 += 32) {
    const int cur = (k0 >> 5) & 1;
    if (k0 + 32 < 3840) stage(k0 + 32, cur ^ 1);
    bf16x8 af[4], bfr[4];
#pragma unroll
    for (int i = 0; i < 4; ++i) {
      af[i] = *(const bf16x8*)(&Alds[cur][(wm * 4 + i) * 512 + roff]);
      bfr[i] = *(const bf16x8*)(&Blds[cur][(wn * 4 + i) * 512 + roff]);
    }
#pragma unroll
    for (int i = 0; i < 4; ++i)
#pragma unroll
      for (int j = 0; j < 4; ++j)
        acc[i][j] = __builtin_amdgcn_mfma_f32_16x16x32_bf16(af[i], bfr[j],
                                                            acc[i][j], 0, 0, 0);
    __syncthreads();
  }

  const int orow = (lane >> 4) * 4;
#pragma unroll
  for (int i = 0; i < 4; ++i) {
#pragma unroll
    for (int j = 0; j < 4; ++j) {
      const int n = n0 + wn * 64 + j * 16 + fr;
#pragma unroll
      for (int rg = 0; rg < 4; ++rg) {
        const int m = m0 + wm * 64 + i * 16 + orow + rg;
        C[(size_t)m * DD + n] = acc[i][j][rg];
      }
    }
  }
}

// counts[r,dst] += 1
__global__ void k_count(const int* __restrict__ et, const int* __restrict__ dst,
                        float* __restrict__ counts) {
  int e = blockIdx.x * 256 + threadIdx.x;
  if (e < NE) atomicAdd(&counts[(size_t)et[e] * NN + dst[e]], 1.0f);
}

// ---- CSR build (by dst) -----------------------------------------------------
__global__ void k_deg(const int* __restrict__ dst, int* __restrict__ deg) {
  int e = blockIdx.x * 256 + threadIdx.x;
  if (e < NE) atomicAdd(&deg[dst[e]], 1);
}

__global__ __launch_bounds__(256) void k_scan(const int* __restrict__ deg,
                                              int* __restrict__ offs,
                                              int* __restrict__ cursor) {
  __shared__ int part[256];
  const int base = threadIdx.x * 64;
  int s = 0;
  for (int i = 0; i < 64; ++i) s += deg[base + i];
  part[threadIdx.x] = s;
  __syncthreads();
  if (threadIdx.x == 0) {
    int run = 0;
    for (int i = 0; i < 256; ++i) { int t = part[i]; part[i] = run; run += t; }
  }
  __syncthreads();
  int run = part[threadIdx.x];
  for (int i = 0; i < 64; ++i) {
    offs[base + i] = run;
    cursor[base + i] = run;
    run += deg[base + i];
  }
  if (threadIdx.x == 255) offs[NN] = run;
}

// elist[slot] = src | (et<<20)
__global__ void k_place(const int* __restrict__ src, const int* __restrict__ dst,
                        const int* __restrict__ et, int* __restrict__ cursor,
                        int* __restrict__ elist) {
  int e = blockIdx.x * 256 + threadIdx.x;
  if (e >= NE) return;
  int d = dst[e];
  int slot = atomicAdd(&cursor[d], 1);
  elist[slot] = src[e] | (et[e] << 20);
}

// ---- single-pass gather, all 4 bases, 4-edge ILP unroll
__global__ __launch_bounds__(192) void k_gather4(const int* __restrict__ offs,
                                                 const int* __restrict__ elist,
                                                 const float* __restrict__ counts,
                                                 const float* __restrict__ compL,
                                                 const unsigned short* __restrict__ x0,
                                                 unsigned short* __restrict__ Y01,
                                                 unsigned short* __restrict__ Y23) {
  const int d = blockIdx.x;
  const int tid = threadIdx.x;
  __shared__ float sw[RR][4];
  if (tid < 4 * RR) {
    const int r = tid >> 2, j = tid & 3;
    const float c = counts[(size_t)r * NN + d];
    sw[r][j] = (c > 0.f) ? compL[r * BB + j] / c : 0.f;
  }
  __syncthreads();
  const int beg = offs[d], end = offs[d + 1];
  float a0[4] = {}, a1[4] = {}, a2[4] = {}, a3[4] = {};
  int e = beg;
  for (; e + 3 < end; e += 4) {
    const int v1 = elist[e], v2 = elist[e + 1], v3 = elist[e + 2], v4 = elist[e + 3];
    const int s1 = v1 & 0xFFFFF, r1 = v1 >> 20;
    const int s2 = v2 & 0xFFFFF, r2 = v2 >> 20;
    const int s3 = v3 & 0xFFFFF, r3 = v3 >> 20;
    const int s4 = v4 & 0xFFFFF, r4 = v4 >> 20;
    ushort4 t1 = *(const ushort4*)&x0[(size_t)s1 * DD + tid * 4];
    ushort4 t2 = *(const ushort4*)&x0[(size_t)s2 * DD + tid * 4];
    ushort4 t3 = *(const ushort4*)&x0[(size_t)s3 * DD + tid * 4];
    ushort4 t4 = *(const ushort4*)&x0[(size_t)s4 * DD + tid * 4];
    const float f1[4] = {b2f(t1.x), b2f(t1.y), b2f(t1.z), b2f(t1.w)};
    const float f2[4] = {b2f(t2.x), b2f(t2.y), b2f(t2.z), b2f(t2.w)};
    const float f3[4] = {b2f(t3.x), b2f(t3.y), b2f(t3.z), b2f(t3.w)};
    const float f4[4] = {b2f(t4.x), b2f(t4.y), b2f(t4.z), b2f(t4.w)};
#pragma unroll
    for (int c = 0; c < 4; ++c) {
      a0[c] += sw[r1][0] * f1[c] + sw[r2][0] * f2[c] + sw[r3][0] * f3[c] + sw[r4][0] * f4[c];
      a1[c] += sw[r1][1] * f1[c] + sw[r2][1] * f2[c] + sw[r3][1] * f3[c] + sw[r4][1] * f4[c];
      a2[c] += sw[r1][2] * f1[c] + sw[r2][2] * f2[c] + sw[r3][2] * f3[c] + sw[r4][2] * f4[c];
      a3[c] += sw[r1][3] * f1[c] + sw[r2][3] * f2[c] + sw[r3][3] * f3[c] + sw[r4][3] * f4[c];
    }
  }
  for (; e < end; ++e) {
    const int v = elist[e];
    const int s = v & 0xFFFFF, r = v >> 20;
    ushort4 t = *(const ushort4*)&x0[(size_t)s * DD + tid * 4];
    const float f[4] = {b2f(t.x), b2f(t.y), b2f(t.z), b2f(t.w)};
#pragma unroll
    for (int c = 0; c < 4; ++c) {
      a0[c] += sw[r][0] * f[c];
      a1[c] += sw[r][1] * f[c];
      a2[c] += sw[r][2] * f[c];
      a3[c] += sw[r][3] * f[c];
    }
  }
  ushort4 o;
  o.x = f2b(a0[0]); o.y = f2b(a0[1]); o.z = f2b(a0[2]); o.w = f2b(a0[3]);
  *(ushort4*)&Y01[(size_t)d * 1536 + tid * 4] = o;
  o.x = f2b(a1[0]); o.y = f2b(a1[1]); o.z = f2b(a1[2]); o.w = f2b(a1[3]);
  *(ushort4*)&Y01[(size_t)d * 1536 + DD + tid * 4] = o;
  o.x = f2b(a2[0]); o.y = f2b(a2[1]); o.z = f2b(a2[2]); o.w = f2b(a2[3]);
  *(ushort4*)&Y23[(size_t)d * 1536 + tid * 4] = o;
  o.x = f2b(a3[0]); o.y = f2b(a3[1]); o.z = f2b(a3[2]); o.w = f2b(a3[3]);
  *(ushort4*)&Y23[(size_t)d * 1536 + DD + tid * 4] = o;
}

// y = relu(xc + conv_bias) + x0 -> yb (bf16, in d_out), col sums/sumsq
__global__ __launch_bounds__(256) void k_epi_stats(const float* __restrict__ xc,
                                                   const unsigned short* __restrict__ x0,
                                                   const float* __restrict__ cbias,
                                                   unsigned short* __restrict__ yb,
                                                   float* __restrict__ sums,
                                                   float* __restrict__ sqs) {
  const int r0 = blockIdx.x * 64;
  float lsum[3] = {0.f, 0.f, 0.f}, lsq[3] = {0.f, 0.f, 0.f};
  float cb[3];
#pragma unroll
  for (int j = 0; j < 3; ++j) cb[j] = cbias[threadIdx.x + j * 256];
  for (int i = 0; i < 64; ++i) {
    const size_t row = r0 + i;
#pragma unroll
    for (int j = 0; j < 3; ++j) {
      const int c = threadIdx.x + j * 256;
      float v = xc[row * DD + c];
      v = fmaxf(v + cb[j], 0.f) + b2f(x0[row * DD + c]);
      yb[row * DD + c] = f2b(v);
      lsum[j] += v;
      lsq[j] += v * v;
    }
  }
#pragma unroll
  for (int j = 0; j < 3; ++j) {
    atomicAdd(&sums[threadIdx.x + j * 256], lsum[j]);
    atomicAdd(&sqs[threadIdx.x + j * 256], lsq[j]);
  }
}

// x0(bf16) = gamma*(yb-mu)*rsqrt(var+eps)+beta, yb bf16
__global__ void k_bn_apply(const unsigned short* __restrict__ yb,
                           const float* __restrict__ gamma,
                           const float* __restrict__ beta,
                           const float* __restrict__ sums,
                           const float* __restrict__ sqs,
                           unsigned short* __restrict__ xout) {
  size_t idx = (size_t)blockIdx.x * 256 + threadIdx.x;
  if (idx >= (size_t)NN * DD) return;
  int c = idx % DD;
  float mu = sums[c] * (1.0f / NN);
  float var = sqs[c] * (1.0f / NN) - mu * mu;
  xout[idx] = f2b(gamma[c] * (b2f(yb[idx]) - mu) * rsqrtf(var + BN_EPS) + beta[c]);
}

// row LayerNorm over HID=1024, f32 in/out, in-place safe
__global__ __launch_bounds__(256) void k_layernorm(const float* __restrict__ hf,
                                                   const float* __restrict__ gamma,
                                                   const float* __restrict__ beta,
                                                   float* __restrict__ out) {
  const int row = blockIdx.x;
  const float* h = hf + (size_t)row * HIDD;
  float v[4];
  float s = 0.f, sq = 0.f;
#pragma unroll
  for (int j = 0; j < 4; ++j) {
    v[j] = h[threadIdx.x + j * 256];
    s += v[j];
    sq += v[j] * v[j];
  }
#pragma unroll
  for (int off = 32; off > 0; off >>= 1) {
    s += __shfl_down(s, off);
    sq += __shfl_down(sq, off);
  }
  __shared__ float ps[4], pq[4];
  const int lane = threadIdx.x & 63, wv = threadIdx.x >> 6;
  if (lane == 0) { ps[wv] = s; pq[wv] = sq; }
  __syncthreads();
  if (threadIdx.x == 0) {
    float ts = ps[0] + ps[1] + ps[2] + ps[3];
    float tq = pq[0] + pq[1] + pq[2] + pq[3];
    float mu = ts * (1.0f / HIDD);
    float var = tq * (1.0f / HIDD) - mu * mu;
    ps[0] = mu;
    pq[0] = rsqrtf(var + LN_EPS);
  }
  __syncthreads();
  const float mu = ps[0], rstd = pq[0];
#pragma unroll
  for (int j = 0; j < 4; ++j) {
    const int c = threadIdx.x + j * 256;
    out[(size_t)row * HIDD + c] = gamma[c] * (v[j] - mu) * rstd + beta[c];
  }
}

extern "C" void kernel_launch(void* const* d_in, const int* in_sizes, int n_in,
                              void* d_out, int out_size, void* d_ws, size_t ws_size,
                              hipStream_t stream) {
  const void* h_text = d_in[0];
  const int* ei      = (const int*)d_in[1];
  const int* etype   = (const int*)d_in[2];
  const void* w_in  = d_in[3];
  const void* b_in  = d_in[4];
  const void* basis = d_in[5];
  const void* comp  = d_in[6];
  const void* root  = d_in[7];
  const void* convb = d_in[8];
  const void* bn_g  = d_in[9];
  const void* bn_b  = d_in[10];
  const void* w_out = d_in[11];
  const void* b_out = d_in[12];
  const void* ln_g  = d_in[13];
  const void* ln_b  = d_in[14];
  float* out = (float*)d_out;      // output is f32

  const int* src = ei;
  const int* dst = ei + NE;

  // ---- ws layout (byte offsets, 64B-aligned). Total 133,406,208 B (~127 MB).
  char* W = (char*)d_ws;
  int*   flags  = (int*)(W + 0);              // 256 B
  float* stats  = (float*)(W + 256);          // 6144 B
  float* fpar   = (float*)(W + 6400);         // 33984 B
  float* f_bin  = fpar;
  float* f_comp = fpar + 768;
  float* f_cb   = fpar + 816;
  float* f_bng  = fpar + 2352;
  float* f_bnb  = fpar + 3888;
  float* f_bout = fpar + 5424;
  float* f_lng  = fpar + 6448;
  float* f_lnb  = fpar + 7472;
  float* counts = (float*)(W + 40384);        // 393216 B
  int*   deg    = (int*)(W + 433600);         // 65536 B
  int*   offs   = (int*)(W + 499136);         // 65600 B (N+1)
  int*   cursor = (int*)(W + 564736);         // 65536 B
  int*   elist  = (int*)(W + 630272);         // 1048576 B
  unsigned short* BTcat = (unsigned short*)(W + 1678848);   // [768][3840] 5898240 B
  unsigned short* x0    = (unsigned short*)(W + 7577088);   // [N][D] 25165824 B
  unsigned short* Y23   = (unsigned short*)(W + 32742912);  // [N][1536] 50331648 B
  float*          xc    = (float*)(W + 83074560);           // [N][D] f32 50331648 B
  const size_t NEED_B = 133406208;
  if (ws_size < NEED_B) {
    k_fill<<<(int)(((long)out_size + 255) / 256), 256, 0, stream>>>(
        out, (long)out_size, (float)(ws_size >> 20) * 100.0f);
    return;
  }

  // ---- d_out scratch map (64 MB) ----
  unsigned short* h16   = (unsigned short*)d_out;            // [N][HID] bf16 (step 1)
  unsigned short* wt_in = (unsigned short*)d_out + 29360128; // byte 58.7M [D][HID]
  unsigned short* Y01   = (unsigned short*)d_out;            // [N][1536] bf16 (layers)
  unsigned short* yb    = (unsigned short*)d_out;            // [N][D] bf16 (epilogue)
  float* hf = out;                                           // [N][HID] f32 (step 4+)
  unsigned short* wt_out = BTcat;                            // [HID][D] bf16 (step 4)

  // 0. dtype detect + batched param conversion
  k_detect<<<1, 256, 0, stream>>>((const unsigned short*)h_text, flags);
  {
    dim3 g(6, 8);
    k_cvt8<<<g, 256, 0, stream>>>(b_in, comp, convb, bn_g, bn_b, b_out, ln_g,
                                  ln_b, fpar, flags);
  }

  // 0b. h16 = bf16(h_text); wt_in = w_in^T
  k_cvtb<<<(NN * HIDD) / 256, 256, 0, stream>>>(h_text, h16, NN * HIDD, flags);
  {
    dim3 g(DD / 64, HIDD / 64);
    k_transpose<<<g, 256, 0, stream>>>(w_in, 0, wt_in, HIDD, DD, HIDD, 0, flags);
  }

  // 1. x0(bf16) = relu(h16 @ w_in + b_in)   [1D grid + XCD swizzle]
  k_mgemm<1, 1, 1><<<(DD / 128) * (NN / 128), 256, 0, stream>>>(
      h16, wt_in, f_bin, x0, NN, DD, HIDD);

  // 2. counts + CSR by dst (reused across layers)
  hipMemsetAsync(counts, 0, (size_t)RR * NN * sizeof(float), stream);
  k_count<<<NE / 256, 256, 0, stream>>>(etype, dst, counts);
  hipMemsetAsync(deg, 0, NN * sizeof(int), stream);
  k_deg<<<NE / 256, 256, 0, stream>>>(dst, deg);
  k_scan<<<1, 256, 0, stream>>>(deg, offs, cursor);
  k_place<<<NE / 256, 256, 0, stream>>>(src, dst, etype, cursor, elist);

  // 3. RGCN layers
  for (int l = 0; l < LL; ++l) {
    const long boff = (long)l * BB * DD * DD;
    const long roff = (long)l * DD * DD;
    const float* compL = f_comp + l * RR * BB;
    const float* cbL   = f_cb + l * DD;
    const float* gL    = f_bng + l * DD;
    const float* bL    = f_bnb + l * DD;

    // single-pass gather: Y01 (d_out) + Y23 (ws)
    k_gather4<<<NN, 192, 0, stream>>>(offs, elist, counts, compL, x0, Y01, Y23);
    // BTcat = [root | B0 | B1 | B2 | B3]^T in one launch
    {
      dim3 g(DD / 64, DD / 64, 5);
      k_tbatch<<<g, 256, 0, stream>>>(root, roff, basis, boff, BTcat, flags);
    }
    // fused GEMM: xc = [x0|Y01|Y23] @ BTcat^T  (K=3840)
    k_mgemm3<<<(DD / 128) * (NN / 128), 256, 0, stream>>>(x0, Y01, Y23, BTcat, xc);

    // epilogue: relu + residual -> yb(bf16, d_out) + stats; BN -> x0(bf16)
    hipMemsetAsync(stats, 0, 2 * DD * sizeof(float), stream);
    k_epi_stats<<<NN / 64, 256, 0, stream>>>(xc, x0, cbL, yb, stats, stats + DD);
    k_bn_apply<<<(int)(((size_t)NN * DD + 255) / 256), 256, 0, stream>>>(
        yb, gL, bL, stats, stats + DD, x0);
  }

  // 4. wt_out = w_out^T (reuses dead BTcat); hf(f32, d_out) = x0 @ w_out + b_out
  {
    dim3 g(HIDD / 64, DD / 64);
    k_transpose<<<g, 256, 0, stream>>>(w_out, 0, wt_out, DD, HIDD, DD, 0, flags);
  }
  k_mgemm<1, 0, 0><<<(HIDD / 128) * (NN / 128), 256, 0, stream>>>(
      x0, wt_out, f_bout, hf, NN, HIDD, DD);

  // 5. LayerNorm in-place in d_out (f32 -> f32)
  k_layernorm<<<NN, 256, 0, stream>>>(hf, f_lng, f_lnb, out);
}

// Round 14
// 750.584 us; speedup vs baseline: 1.2304x; 1.2304x over previous
//
#include <hip/hip_runtime.h>
#include <hip/hip_bf16.h>

#define NN 16384      // nodes
#define NE 262144     // edges
#define HIDD 1024
#define DD 768
#define RR 6
#define BB 4
#define LL 2
#define BN_EPS 1e-5f
#define LN_EPS 1e-5f

typedef __attribute__((ext_vector_type(8))) short bf16x8;
typedef __attribute__((ext_vector_type(4))) float f32x4;

__device__ __forceinline__ float b2f(unsigned short u) {
  union { unsigned int i; float f; } c;
  c.i = ((unsigned int)u) << 16;
  return c.f;
}
__device__ __forceinline__ unsigned short f2b(float f) {  // RNE
  union { float f; unsigned int u; } c;
  c.f = f;
  unsigned int x = c.u;
  x += 0x7FFFu + ((x >> 16) & 1u);
  return (unsigned short)(x >> 16);
}

__device__ __forceinline__ void gll16(const unsigned short* g, unsigned short* l) {
  __builtin_amdgcn_global_load_lds(
      (const __attribute__((address_space(1))) unsigned int*)g,
      (__attribute__((address_space(3))) unsigned int*)l, 16, 0, 0);
}

// dtype detector: flag=1 -> inputs f32, flag=0 -> inputs bf16.
__global__ void k_detect(const unsigned short* __restrict__ h, int* __restrict__ flag) {
  __shared__ int sh[256];
  int cnt = 0;
  for (int k = 0; k < 256; ++k) {
    ushort4 t = *(const ushort4*)&h[(size_t)(k * 256 + threadIdx.x) * 4];
    if ((t.x & 0x7F80) == 0x7F80) cnt++;
    if ((t.y & 0x7F80) == 0x7F80) cnt++;
    if ((t.z & 0x7F80) == 0x7F80) cnt++;
    if ((t.w & 0x7F80) == 0x7F80) cnt++;
  }
  sh[threadIdx.x] = cnt;
  __syncthreads();
  if (threadIdx.x == 0) {
    int t = 0;
    for (int i = 0; i < 256; ++i) t += sh[i];
    flag[0] = (t > 16) ? 1 : 0;
  }
}

// MODE: 0 = raw input (flag-dependent), 1 = f32, 2 = bf16
template <int MODE>
__device__ __forceinline__ float load1t(const void* p, size_t i, int isf32) {
  if (MODE == 1 || (MODE == 0 && isf32)) return ((const float*)p)[i];
  return b2f(((const unsigned short*)p)[i]);
}

// batched param conversion: 8 segments -> fpar
__global__ void k_cvt8(const void* s0, const void* s1, const void* s2, const void* s3,
                       const void* s4, const void* s5, const void* s6, const void* s7,
                       float* __restrict__ fpar, const int* __restrict__ flagp) {
  const int isf32 = flagp[0];
  const int seg = blockIdx.y;
  const int lens[8] = {768, 48, 1536, 1536, 1536, 1024, 1024, 1024};
  const int offs_[8] = {0, 768, 816, 2352, 3888, 5424, 6448, 7472};
  const void* srcs[8] = {s0, s1, s2, s3, s4, s5, s6, s7};
  int i = blockIdx.x * 256 + threadIdx.x;
  if (i < lens[seg]) fpar[offs_[seg] + i] = load1t<0>(srcs[seg], i, isf32);
}

// raw input -> bf16 copy
__global__ void k_cvtb(const void* __restrict__ in, unsigned short* __restrict__ out,
                       int n, const int* __restrict__ flagp) {
  const int isf32 = flagp[0];
  int i = blockIdx.x * 256 + threadIdx.x;
  if (i < n) out[i] = f2b(load1t<0>(in, (size_t)i, isf32));
}

// diagnostic fill (f32 out)
__global__ void k_fill(float* __restrict__ out, long n, float val) {
  long i = (long)blockIdx.x * 256 + threadIdx.x;
  if (i < n) out[i] = val;
}

// LDS-tiled transpose: src [I][J] (flag dtype) -> dst[j*dstStride + dstOff + i] bf16.
__global__ __launch_bounds__(256) void k_transpose(const void* __restrict__ src,
                                                   long ioff,
                                                   unsigned short* __restrict__ dst,
                                                   int I, int J, int dstStride,
                                                   int dstOff,
                                                   const int* __restrict__ flagp) {
  const int isf32 = flagp[0];
  __shared__ unsigned short t[64][65];
  const int j0 = blockIdx.x * 64, i0 = blockIdx.y * 64;
  const int tx = threadIdx.x & 63, ty = threadIdx.x >> 6;
  for (int rr = ty; rr < 64; rr += 4)
    t[rr][tx] = f2b(load1t<0>(src, (size_t)ioff + (size_t)(i0 + rr) * J + j0 + tx, isf32));
  __syncthreads();
  for (int rr = ty; rr < 64; rr += 4)
    dst[(size_t)(j0 + rr) * dstStride + dstOff + i0 + tx] = t[tx][rr];
}

// batched: BTcat[n][z*768 + k] = W_z[k][n], z=0 root, z=1..4 basis[z-1]
__global__ __launch_bounds__(256) void k_tbatch(const void* __restrict__ root, long roff,
                                                const void* __restrict__ basis, long boff,
                                                unsigned short* __restrict__ BT,
                                                const int* __restrict__ flagp) {
  const int isf32 = flagp[0];
  const int z = blockIdx.z;
  const void* src = (z == 0) ? root : basis;
  const long off = (z == 0) ? roff : boff + (long)(z - 1) * DD * DD;
  __shared__ unsigned short t[64][65];
  const int j0 = blockIdx.x * 64, i0 = blockIdx.y * 64;
  const int tx = threadIdx.x & 63, ty = threadIdx.x >> 6;
  for (int rr = ty; rr < 64; rr += 4)
    t[rr][tx] = f2b(load1t<0>(src, (size_t)off + (size_t)(i0 + rr) * DD + j0 + tx, isf32));
  __syncthreads();
  for (int rr = ty; rr < 64; rr += 4)
    BT[(size_t)(j0 + rr) * (5 * DD) + z * DD + i0 + tx] = t[tx][rr];
}

// ---------------------------------------------------------------------------
// MFMA bf16 GEMM: C[M,N] = A[M,K] @ Bt[N,K]^T (+bias)(relu)
// 128x128 tile, 4 waves, BK=64 (2x32 sub-chunks per barrier pair -> half the
// barriers of BK=32), 16x16x32 MFMA, global_load_lds staging, XOR bank
// permutation (2-way = free), bijective XCD swizzle. R12-proven K-loop shape.
// ---------------------------------------------------------------------------
template <int BIAS, int RELU, int OUTB>
__global__ __launch_bounds__(256) void k_mgemm(const unsigned short* __restrict__ A,
                                               const unsigned short* __restrict__ Bt,
                                               const float* __restrict__ bias,
                                               void* __restrict__ C,
                                               int M, int Nn, int K) {
  __shared__ __align__(16) unsigned short Alds[2][128 * 32];
  __shared__ __align__(16) unsigned short Blds[2][128 * 32];
  const int tid = threadIdx.x;
  const int lane = tid & 63, w = tid >> 6;
  const int wm = w >> 1, wn = w & 1;
  const int fr = lane & 15, kg = lane >> 4;
  const int nwg = gridDim.x;
  int id = blockIdx.x;
  if ((nwg & 7) == 0) id = (id & 7) * (nwg >> 3) + (id >> 3);
  const int gx = Nn >> 7;
  const int m0 = (id / gx) * 128, n0 = (id % gx) * 128;

  const int srow = w * 16 + (lane >> 2);
  const int sslot = (lane & 3) ^ ((lane >> 3) & 3);
  const unsigned short* ga = A + (size_t)(m0 + srow) * K + sslot * 8;
  const unsigned short* ga2 = ga + (size_t)64 * K;
  const unsigned short* gb = Bt + (size_t)(n0 + srow) * K + sslot * 8;
  const unsigned short* gb2 = gb + (size_t)64 * K;
  const int wo = w * 512;
  const int roff = fr * 32 + ((kg ^ ((fr >> 1) & 3)) * 8);

  f32x4 acc[4][4] = {};

  for (int k0 = 0; k0 < K; k0 += 64) {
    gll16(ga + k0, &Alds[0][wo]);
    gll16(ga2 + k0, &Alds[0][wo + 2048]);
    gll16(gb + k0, &Blds[0][wo]);
    gll16(gb2 + k0, &Blds[0][wo + 2048]);
    gll16(ga + k0 + 32, &Alds[1][wo]);
    gll16(ga2 + k0 + 32, &Alds[1][wo + 2048]);
    gll16(gb + k0 + 32, &Blds[1][wo]);
    gll16(gb2 + k0 + 32, &Blds[1][wo + 2048]);
    __syncthreads();
#pragma unroll
    for (int kh = 0; kh < 2; ++kh) {
      bf16x8 af[4], bfr[4];
#pragma unroll
      for (int i = 0; i < 4; ++i) {
        af[i] = *(const bf16x8*)(&Alds[kh][(wm * 4 + i) * 512 + roff]);
        bfr[i] = *(const bf16x8*)(&Blds[kh][(wn * 4 + i) * 512 + roff]);
      }
#pragma unroll
      for (int i = 0; i < 4; ++i)
#pragma unroll
        for (int j = 0; j < 4; ++j)
          acc[i][j] = __builtin_amdgcn_mfma_f32_16x16x32_bf16(af[i], bfr[j],
                                                              acc[i][j], 0, 0, 0);
    }
    __syncthreads();
  }

  const int orow = (lane >> 4) * 4;
#pragma unroll
  for (int i = 0; i < 4; ++i) {
#pragma unroll
    for (int j = 0; j < 4; ++j) {
      const int n = n0 + wn * 64 + j * 16 + fr;
      const float bv = BIAS ? bias[n] : 0.f;
#pragma unroll
      for (int rg = 0; rg < 4; ++rg) {
        const int m = m0 + wm * 64 + i * 16 + orow + rg;
        const size_t off = (size_t)m * Nn + n;
        float v = acc[i][j][rg] + bv;
        if (RELU) v = fmaxf(v, 0.f);
        if (OUTB) ((unsigned short*)C)[off] = f2b(v);
        else      ((float*)C)[off] = v;
      }
    }
  }
}

// ---------------------------------------------------------------------------
// Fused layer GEMM + epilogue:
//   yb[N][768](bf16) = relu([x0|Y01|Y23] @ BTcat^T + conv_bias) + x0
//   + per-column sums/sumsq (LDS-reduced, then global atomics)
// BK=64, same staging/swizzle as k_mgemm. grid = 768.
// ---------------------------------------------------------------------------
__global__ __launch_bounds__(256) void k_mgemm3(const unsigned short* __restrict__ x0,
                                                const unsigned short* __restrict__ Y01,
                                                const unsigned short* __restrict__ Y23,
                                                const unsigned short* __restrict__ BT,
                                                const float* __restrict__ cbias,
                                                unsigned short* __restrict__ yb,
                                                float* __restrict__ sums,
                                                float* __restrict__ sqs) {
  __shared__ __align__(16) unsigned short Alds[2][128 * 32];
  __shared__ __align__(16) unsigned short Blds[2][128 * 32];
  __shared__ float csum[128], csq[128];
  const int tid = threadIdx.x;
  const int lane = tid & 63, w = tid >> 6;
  const int wm = w >> 1, wn = w & 1;
  const int fr = lane & 15, kg = lane >> 4;
  const int nwg = gridDim.x;        // 768
  int id = blockIdx.x;
  id = (id & 7) * (nwg >> 3) + (id >> 3);
  const int m0 = (id / 6) * 128, n0 = (id % 6) * 128;

  const int srow = w * 16 + (lane >> 2);
  const int sslot = (lane & 3) ^ ((lane >> 3) & 3);
  const unsigned short* gxp = x0 + (size_t)(m0 + srow) * DD + sslot * 8;
  const unsigned short* gxp2 = gxp + (size_t)64 * DD;
  const unsigned short* gy = Y01 + (size_t)(m0 + srow) * 1536 + sslot * 8;
  const unsigned short* gy2 = gy + (size_t)64 * 1536;
  const unsigned short* gz = Y23 + (size_t)(m0 + srow) * 1536 + sslot * 8;
  const unsigned short* gz2 = gz + (size_t)64 * 1536;
  const unsigned short* gb = BT + (size_t)(n0 + srow) * 3840 + sslot * 8;
  const unsigned short* gb2 = gb + (size_t)64 * 3840;
  const int wo = w * 512;
  const int roff = fr * 32 + ((kg ^ ((fr >> 1) & 3)) * 8);

  f32x4 acc[4][4] = {};

  // K-loop, BK=64 (segment boundaries 768/2304 are multiples of 64)
  for (int k0 = 0; k0 < 3840; k0 += 64) {
    const unsigned short *pa, *pa2;
    long ko;
    if (k0 < 768)       { pa = gxp; pa2 = gxp2; ko = k0; }
    else if (k0 < 2304) { pa = gy;  pa2 = gy2;  ko = k0 - 768; }
    else                { pa = gz;  pa2 = gz2;  ko = k0 - 2304; }
    gll16(pa + ko, &Alds[0][wo]);
    gll16(pa2 + ko, &Alds[0][wo + 2048]);
    gll16(pa + ko + 32, &Alds[1][wo]);
    gll16(pa2 + ko + 32, &Alds[1][wo + 2048]);
    gll16(gb + k0, &Blds[0][wo]);
    gll16(gb2 + k0, &Blds[0][wo + 2048]);
    gll16(gb + k0 + 32, &Blds[1][wo]);
    gll16(gb2 + k0 + 32, &Blds[1][wo + 2048]);
    __syncthreads();
#pragma unroll
    for (int kh = 0; kh < 2; ++kh) {
      bf16x8 af[4], bfr[4];
#pragma unroll
      for (int i = 0; i < 4; ++i) {
        af[i] = *(const bf16x8*)(&Alds[kh][(wm * 4 + i) * 512 + roff]);
        bfr[i] = *(const bf16x8*)(&Blds[kh][(wn * 4 + i) * 512 + roff]);
      }
#pragma unroll
      for (int i = 0; i < 4; ++i)
#pragma unroll
        for (int j = 0; j < 4; ++j)
          acc[i][j] = __builtin_amdgcn_mfma_f32_16x16x32_bf16(af[i], bfr[j],
                                                              acc[i][j], 0, 0, 0);
    }
    __syncthreads();
  }

  // fused epilogue: v = relu(acc + cb) + x0; write yb bf16; column stats
  if (tid < 128) { csum[tid] = 0.f; csq[tid] = 0.f; }
  __syncthreads();
  const int orow = (lane >> 4) * 4;
#pragma unroll
  for (int j = 0; j < 4; ++j) {
    const int nloc = wn * 64 + j * 16 + fr;
    const int n = n0 + nloc;
    const float cb = cbias[n];
    float ps = 0.f, pq = 0.f;
#pragma unroll
    for (int i = 0; i < 4; ++i) {
#pragma unroll
      for (int rg = 0; rg < 4; ++rg) {
        const int m = m0 + wm * 64 + i * 16 + orow + rg;
        float v = fmaxf(acc[i][j][rg] + cb, 0.f) + b2f(x0[(size_t)m * DD + n]);
        yb[(size_t)m * DD + n] = f2b(v);
        ps += v;
        pq += v * v;
      }
    }
    atomicAdd(&csum[nloc], ps);
    atomicAdd(&csq[nloc], pq);
  }
  __syncthreads();
  if (tid < 128) {
    atomicAdd(&sums[n0 + tid], csum[tid]);
    atomicAdd(&sqs[n0 + tid], csq[tid]);
  }
}

// counts[r,dst] += 1
__global__ void k_count(const int* __restrict__ et, const int* __restrict__ dst,
                        float* __restrict__ counts) {
  int e = blockIdx.x * 256 + threadIdx.x;
  if (e < NE) atomicAdd(&counts[(size_t)et[e] * NN + dst[e]], 1.0f);
}

// ---- CSR build (by dst) -----------------------------------------------------
__global__ void k_deg(const int* __restrict__ dst, int* __restrict__ deg) {
  int e = blockIdx.x * 256 + threadIdx.x;
  if (e < NE) atomicAdd(&deg[dst[e]], 1);
}

__global__ __launch_bounds__(256) void k_scan(const int* __restrict__ deg,
                                              int* __restrict__ offs,
                                              int* __restrict__ cursor) {
  __shared__ int part[256];
  const int base = threadIdx.x * 64;
  int s = 0;
  for (int i = 0; i < 64; ++i) s += deg[base + i];
  part[threadIdx.x] = s;
  __syncthreads();
  if (threadIdx.x == 0) {
    int run = 0;
    for (int i = 0; i < 256; ++i) { int t = part[i]; part[i] = run; run += t; }
  }
  __syncthreads();
  int run = part[threadIdx.x];
  for (int i = 0; i < 64; ++i) {
    offs[base + i] = run;
    cursor[base + i] = run;
    run += deg[base + i];
  }
  if (threadIdx.x == 255) offs[NN] = run;
}

// elist[slot] = src | (et<<20)
__global__ void k_place(const int* __restrict__ src, const int* __restrict__ dst,
                        const int* __restrict__ et, int* __restrict__ cursor,
                        int* __restrict__ elist) {
  int e = blockIdx.x * 256 + threadIdx.x;
  if (e >= NE) return;
  int d = dst[e];
  int slot = atomicAdd(&cursor[d], 1);
  elist[slot] = src[e] | (et[e] << 20);
}

// ---- single-pass gather, all 4 bases, 4-edge ILP unroll
__global__ __launch_bounds__(192) void k_gather4(const int* __restrict__ offs,
                                                 const int* __restrict__ elist,
                                                 const float* __restrict__ counts,
                                                 const float* __restrict__ compL,
                                                 const unsigned short* __restrict__ x0,
                                                 unsigned short* __restrict__ Y01,
                                                 unsigned short* __restrict__ Y23) {
  const int d = blockIdx.x;
  const int tid = threadIdx.x;
  __shared__ float sw[RR][4];
  if (tid < 4 * RR) {
    const int r = tid >> 2, j = tid & 3;
    const float c = counts[(size_t)r * NN + d];
    sw[r][j] = (c > 0.f) ? compL[r * BB + j] / c : 0.f;
  }
  __syncthreads();
  const int beg = offs[d], end = offs[d + 1];
  float a0[4] = {}, a1[4] = {}, a2[4] = {}, a3[4] = {};
  int e = beg;
  for (; e + 3 < end; e += 4) {
    const int v1 = elist[e], v2 = elist[e + 1], v3 = elist[e + 2], v4 = elist[e + 3];
    const int s1 = v1 & 0xFFFFF, r1 = v1 >> 20;
    const int s2 = v2 & 0xFFFFF, r2 = v2 >> 20;
    const int s3 = v3 & 0xFFFFF, r3 = v3 >> 20;
    const int s4 = v4 & 0xFFFFF, r4 = v4 >> 20;
    ushort4 t1 = *(const ushort4*)&x0[(size_t)s1 * DD + tid * 4];
    ushort4 t2 = *(const ushort4*)&x0[(size_t)s2 * DD + tid * 4];
    ushort4 t3 = *(const ushort4*)&x0[(size_t)s3 * DD + tid * 4];
    ushort4 t4 = *(const ushort4*)&x0[(size_t)s4 * DD + tid * 4];
    const float f1[4] = {b2f(t1.x), b2f(t1.y), b2f(t1.z), b2f(t1.w)};
    const float f2[4] = {b2f(t2.x), b2f(t2.y), b2f(t2.z), b2f(t2.w)};
    const float f3[4] = {b2f(t3.x), b2f(t3.y), b2f(t3.z), b2f(t3.w)};
    const float f4[4] = {b2f(t4.x), b2f(t4.y), b2f(t4.z), b2f(t4.w)};
#pragma unroll
    for (int c = 0; c < 4; ++c) {
      a0[c] += sw[r1][0] * f1[c] + sw[r2][0] * f2[c] + sw[r3][0] * f3[c] + sw[r4][0] * f4[c];
      a1[c] += sw[r1][1] * f1[c] + sw[r2][1] * f2[c] + sw[r3][1] * f3[c] + sw[r4][1] * f4[c];
      a2[c] += sw[r1][2] * f1[c] + sw[r2][2] * f2[c] + sw[r3][2] * f3[c] + sw[r4][2] * f4[c];
      a3[c] += sw[r1][3] * f1[c] + sw[r2][3] * f2[c] + sw[r3][3] * f3[c] + sw[r4][3] * f4[c];
    }
  }
  for (; e < end; ++e) {
    const int v = elist[e];
    const int s = v & 0xFFFFF, r = v >> 20;
    ushort4 t = *(const ushort4*)&x0[(size_t)s * DD + tid * 4];
    const float f[4] = {b2f(t.x), b2f(t.y), b2f(t.z), b2f(t.w)};
#pragma unroll
    for (int c = 0; c < 4; ++c) {
      a0[c] += sw[r][0] * f[c];
      a1[c] += sw[r][1] * f[c];
      a2[c] += sw[r][2] * f[c];
      a3[c] += sw[r][3] * f[c];
    }
  }
  ushort4 o;
  o.x = f2b(a0[0]); o.y = f2b(a0[1]); o.z = f2b(a0[2]); o.w = f2b(a0[3]);
  *(ushort4*)&Y01[(size_t)d * 1536 + tid * 4] = o;
  o.x = f2b(a1[0]); o.y = f2b(a1[1]); o.z = f2b(a1[2]); o.w = f2b(a1[3]);
  *(ushort4*)&Y01[(size_t)d * 1536 + DD + tid * 4] = o;
  o.x = f2b(a2[0]); o.y = f2b(a2[1]); o.z = f2b(a2[2]); o.w = f2b(a2[3]);
  *(ushort4*)&Y23[(size_t)d * 1536 + tid * 4] = o;
  o.x = f2b(a3[0]); o.y = f2b(a3[1]); o.z = f2b(a3[2]); o.w = f2b(a3[3]);
  *(ushort4*)&Y23[(size_t)d * 1536 + DD + tid * 4] = o;
}

// x0(bf16) = gamma*(yb-mu)*rsqrt(var+eps)+beta, yb bf16 (in ws)
__global__ void k_bn_apply(const unsigned short* __restrict__ yb,
                           const float* __restrict__ gamma,
                           const float* __restrict__ beta,
                           const float* __restrict__ sums,
                           const float* __restrict__ sqs,
                           unsigned short* __restrict__ xout) {
  size_t idx = (size_t)blockIdx.x * 256 + threadIdx.x;
  if (idx >= (size_t)NN * DD) return;
  int c = idx % DD;
  float mu = sums[c] * (1.0f / NN);
  float var = sqs[c] * (1.0f / NN) - mu * mu;
  xout[idx] = f2b(gamma[c] * (b2f(yb[idx]) - mu) * rsqrtf(var + BN_EPS) + beta[c]);
}

// row LayerNorm over HID=1024, f32 in/out, in-place safe
__global__ __launch_bounds__(256) void k_layernorm(const float* __restrict__ hf,
                                                   const float* __restrict__ gamma,
                                                   const float* __restrict__ beta,
                                                   float* __restrict__ out) {
  const int row = blockIdx.x;
  const float* h = hf + (size_t)row * HIDD;
  float v[4];
  float s = 0.f, sq = 0.f;
#pragma unroll
  for (int j = 0; j < 4; ++j) {
    v[j] = h[threadIdx.x + j * 256];
    s += v[j];
    sq += v[j] * v[j];
  }
#pragma unroll
  for (int off = 32; off > 0; off >>= 1) {
    s += __shfl_down(s, off);
    sq += __shfl_down(sq, off);
  }
  __shared__ float ps[4], pq[4];
  const int lane = threadIdx.x & 63, wv = threadIdx.x >> 6;
  if (lane == 0) { ps[wv] = s; pq[wv] = sq; }
  __syncthreads();
  if (threadIdx.x == 0) {
    float ts = ps[0] + ps[1] + ps[2] + ps[3];
    float tq = pq[0] + pq[1] + pq[2] + pq[3];
    float mu = ts * (1.0f / HIDD);
    float var = tq * (1.0f / HIDD) - mu * mu;
    ps[0] = mu;
    pq[0] = rsqrtf(var + LN_EPS);
  }
  __syncthreads();
  const float mu = ps[0], rstd = pq[0];
#pragma unroll
  for (int j = 0; j < 4; ++j) {
    const int c = threadIdx.x + j * 256;
    out[(size_t)row * HIDD + c] = gamma[c] * (v[j] - mu) * rstd + beta[c];
  }
}

extern "C" void kernel_launch(void* const* d_in, const int* in_sizes, int n_in,
                              void* d_out, int out_size, void* d_ws, size_t ws_size,
                              hipStream_t stream) {
  const void* h_text = d_in[0];
  const int* ei      = (const int*)d_in[1];
  const int* etype   = (const int*)d_in[2];
  const void* w_in  = d_in[3];
  const void* b_in  = d_in[4];
  const void* basis = d_in[5];
  const void* comp  = d_in[6];
  const void* root  = d_in[7];
  const void* convb = d_in[8];
  const void* bn_g  = d_in[9];
  const void* bn_b  = d_in[10];
  const void* w_out = d_in[11];
  const void* b_out = d_in[12];
  const void* ln_g  = d_in[13];
  const void* ln_b  = d_in[14];
  float* out = (float*)d_out;      // output is f32

  const int* src = ei;
  const int* dst = ei + NE;

  // ---- ws layout (byte offsets, 64B-aligned). Total 133,406,208 B (~127 MB).
  char* W = (char*)d_ws;
  int*   flags  = (int*)(W + 0);              // 256 B
  float* stats  = (float*)(W + 256);          // 6144 B
  float* fpar   = (float*)(W + 6400);         // 33984 B
  float* f_bin  = fpar;
  float* f_comp = fpar + 768;
  float* f_cb   = fpar + 816;
  float* f_bng  = fpar + 2352;
  float* f_bnb  = fpar + 3888;
  float* f_bout = fpar + 5424;
  float* f_lng  = fpar + 6448;
  float* f_lnb  = fpar + 7472;
  float* counts = (float*)(W + 40384);        // 393216 B
  int*   deg    = (int*)(W + 433600);         // 65536 B
  int*   offs   = (int*)(W + 499136);         // 65600 B (N+1)
  int*   cursor = (int*)(W + 564736);         // 65536 B
  int*   elist  = (int*)(W + 630272);         // 1048576 B
  unsigned short* BTcat = (unsigned short*)(W + 1678848);   // [768][3840] 5898240 B
  unsigned short* x0    = (unsigned short*)(W + 7577088);   // [N][D] 25165824 B
  unsigned short* Y23   = (unsigned short*)(W + 32742912);  // [N][1536] 50331648 B
  unsigned short* yb_ws = (unsigned short*)(W + 83074560);  // [N][D] bf16 (old xc slot)
  const size_t NEED_B = 133406208;
  if (ws_size < NEED_B) {
    k_fill<<<(int)(((long)out_size + 255) / 256), 256, 0, stream>>>(
        out, (long)out_size, (float)(ws_size >> 20) * 100.0f);
    return;
  }

  // ---- d_out scratch map (64 MB) ----
  unsigned short* h16   = (unsigned short*)d_out;            // [N][HID] bf16 (step 1)
  unsigned short* wt_in = (unsigned short*)d_out + 29360128; // byte 58.7M [D][HID]
  unsigned short* Y01   = (unsigned short*)d_out;            // [N][1536] bf16 (layers)
  float* hf = out;                                           // [N][HID] f32 (step 4+)
  unsigned short* wt_out = BTcat;                            // [HID][D] bf16 (step 4)

  // 0. dtype detect + batched param conversion
  k_detect<<<1, 256, 0, stream>>>((const unsigned short*)h_text, flags);
  {
    dim3 g(6, 8);
    k_cvt8<<<g, 256, 0, stream>>>(b_in, comp, convb, bn_g, bn_b, b_out, ln_g,
                                  ln_b, fpar, flags);
  }

  // 0b. h16 = bf16(h_text); wt_in = w_in^T
  k_cvtb<<<(NN * HIDD) / 256, 256, 0, stream>>>(h_text, h16, NN * HIDD, flags);
  {
    dim3 g(DD / 64, HIDD / 64);
    k_transpose<<<g, 256, 0, stream>>>(w_in, 0, wt_in, HIDD, DD, HIDD, 0, flags);
  }

  // 1. x0(bf16) = relu(h16 @ w_in + b_in)
  k_mgemm<1, 1, 1><<<(DD / 128) * (NN / 128), 256, 0, stream>>>(
      h16, wt_in, f_bin, x0, NN, DD, HIDD);

  // 2. counts + CSR by dst (reused across layers)
  hipMemsetAsync(counts, 0, (size_t)RR * NN * sizeof(float), stream);
  k_count<<<NE / 256, 256, 0, stream>>>(etype, dst, counts);
  hipMemsetAsync(deg, 0, NN * sizeof(int), stream);
  k_deg<<<NE / 256, 256, 0, stream>>>(dst, deg);
  k_scan<<<1, 256, 0, stream>>>(deg, offs, cursor);
  k_place<<<NE / 256, 256, 0, stream>>>(src, dst, etype, cursor, elist);

  // 3. RGCN layers
  for (int l = 0; l < LL; ++l) {
    const long boff = (long)l * BB * DD * DD;
    const long roff = (long)l * DD * DD;
    const float* compL = f_comp + l * RR * BB;
    const float* cbL   = f_cb + l * DD;
    const float* gL    = f_bng + l * DD;
    const float* bL    = f_bnb + l * DD;

    // single-pass gather: Y01 (d_out) + Y23 (ws)
    k_gather4<<<NN, 192, 0, stream>>>(offs, elist, counts, compL, x0, Y01, Y23);
    // BTcat = [root | B0 | B1 | B2 | B3]^T in one launch
    {
      dim3 g(DD / 64, DD / 64, 5);
      k_tbatch<<<g, 256, 0, stream>>>(root, roff, basis, boff, BTcat, flags);
    }
    // fused GEMM + epilogue: yb(bf16, ws) + column stats
    hipMemsetAsync(stats, 0, 2 * DD * sizeof(float), stream);
    k_mgemm3<<<(DD / 128) * (NN / 128), 256, 0, stream>>>(
        x0, Y01, Y23, BTcat, cbL, yb_ws, stats, stats + DD);
    // BN -> x0(bf16)
    k_bn_apply<<<(int)(((size_t)NN * DD + 255) / 256), 256, 0, stream>>>(
        yb_ws, gL, bL, stats, stats + DD, x0);
  }

  // 4. wt_out = w_out^T (reuses dead BTcat); hf(f32, d_out) = x0 @ w_out + b_out
  {
    dim3 g(HIDD / 64, DD / 64);
    k_transpose<<<g, 256, 0, stream>>>(w_out, 0, wt_out, DD, HIDD, DD, 0, flags);
  }
  k_mgemm<1, 0, 0><<<(HIDD / 128) * (NN / 128), 256, 0, stream>>>(
      x0, wt_out, f_bout, hf, NN, HIDD, DD);

  // 5. LayerNorm in-place in d_out (f32 -> f32)
  k_layernorm<<<NN, 256, 0, stream>>>(hf, f_lng, f_lnb, out);
}